// Round 6
// baseline (1281.900 us; speedup 1.0000x reference)
//
#include <hip/hip_runtime.h>
#include <hip/hip_bf16.h>
#include <stdint.h>

#define SEQ      4096
#define BATCH    4
#define HIDDEN   2048
#define CHANNELS 4096
#define MTOT     (BATCH*SEQ)   // 16384

typedef __bf16 bf16;
typedef __bf16 bf16x8 __attribute__((ext_vector_type(8)));
typedef float  f32x4  __attribute__((ext_vector_type(4)));

// async 16B global->LDS (wave-uniform base + lane*16 on LDS side)
#define GLDS16(g, l) __builtin_amdgcn_global_load_lds(                      \
    (const __attribute__((address_space(1))) void*)(g),                     \
    (__attribute__((address_space(3))) void*)(l), 16, 0, 0)

union B8 { uint4 v; bf16 h[8]; };

template <int M> struct IC { static constexpr int value = M; };

// barrier WITHOUT implicit waitcnt drain; sched_barriers pin code motion
#define SBAR() do {                                   \
    __builtin_amdgcn_sched_barrier(0);                \
    __builtin_amdgcn_s_barrier();                     \
    asm volatile("" ::: "memory");                    \
    __builtin_amdgcn_sched_barrier(0); } while (0)
// counted vmcnt wait (literal) + code-motion pin
#define VMCNT(n) do {                                 \
    asm volatile("s_waitcnt vmcnt(" #n ")" ::: "memory"); \
    __builtin_amdgcn_sched_barrier(0); } while (0)

// ---------------------------------------------------------------------------
// fp32 -> bf16 cast, 8 elems/thread
// ---------------------------------------------------------------------------
__global__ __launch_bounds__(256)
void cast_f32_to_bf16(const float* __restrict__ in, bf16* __restrict__ out) {
    const long long i = (long long)blockIdx.x * 256 + threadIdx.x;
    const float4 a = ((const float4*)in)[2 * i];
    const float4 b = ((const float4*)in)[2 * i + 1];
    B8 o;
    o.h[0] = (bf16)a.x; o.h[1] = (bf16)a.y; o.h[2] = (bf16)a.z; o.h[3] = (bf16)a.w;
    o.h[4] = (bf16)b.x; o.h[5] = (bf16)b.y; o.h[6] = (bf16)b.z; o.h[7] = (bf16)b.w;
    *(uint4*)(out + 8 * i) = o.v;
}

// ---------------------------------------------------------------------------
// NT GEMM, 256x256 tile, BK=64, 512 thr (8 waves: 2M x 4N), 8-slot pipeline,
// v5 = v4 with the tail staging fixed.
//
// Pipeline: per phase [6 ds_read_b128 for NEXT phase][1 STAGE][MFMA on
// prev-phase regs][counted vmcnt][barrier]. vmcnt BEFORE the barrier (own
// loads certified, barrier makes it collective — v3's NaN was waiting
// after the barrier).
//
// Stage σ issues at phase σ-6 -> tile NT-2 (MODE 1) MUST still issue
// stages 4NT-2, 4NT-1 at its q0/q1 (v4 guarded all stages with MODE==0 ->
// last tile's A1/B1 never staged -> stale data, absmax 4e-2). Waits:
//   end of (q0,q1,q2,q3):  steady: -,6,6,4   MODE 1: -,6,4,0   MODE 2: none.
// MODE 1 end-q3 must be vmcnt(0): outstanding there = {4NT-2,4NT-1}, both
// read by MODE 2's q0.
// LDS WAR: every slot's last reader drains (lgkm before its MFMA use)
// >=2 barriers before the overwriting stage issues. Cross-tile carried
// frags (a0,b0) ping-pong via static names (rule #20).
// ---------------------------------------------------------------------------
template <typename OutT, int N, int K>
__global__ __launch_bounds__(512, 2)
void gemm256_bt_bias(const bf16* __restrict__ A, const bf16* __restrict__ B,
                     const float* __restrict__ bias, OutT* __restrict__ C) {
    constexpr int NT    = K / 64;        // K-tiles (even: 32 or 64)
    constexpr int NTILE = N / 256;       // N-tiles (power of 2)
    __shared__ bf16 lds[8][128 * 64];    // 128 KiB

    const int tid  = threadIdx.x;
    const int lane = tid & 63;
    const int wave = tid >> 6;
    const int wr   = wave >> 2;          // 0..1
    const int wc   = wave & 3;           // 0..3
    const int quad = lane >> 4;          // 0..3
    const int lrow = lane & 15;          // 0..15

    // XCD-chunked bijective swizzle (nwg % 8 == 0), N fastest within chunk.
    const int nwg = gridDim.x;
    const int bid = blockIdx.x;
    const int swz = (bid & 7) * (nwg >> 3) + (bid >> 3);
    const int ni  = swz % NTILE;
    const int mi  = swz / NTILE;
    const long long bm = (long long)mi * 256;
    const long long bn = (long long)ni * 256;

    f32x4 acc[2][2][4][2] = {};          // 128 regs
    // cross-tile carried fragment buffers (ping-pong A/B sets)
    bf16x8 a0A[4][2], a0B[4][2];         // A-lo of cur/next tile
    bf16x8 b0A[2][2], b0B[2][2];         // B-lo of cur/next tile

    auto STAGE = [&](int s) {
        const int kind = s & 3;
        const int slot = s & 7;
        const int kt   = (s >> 2) * 64;
        const bf16* src = (kind & 1) ? B : A;
        const long long rbase = ((kind & 1) ? bn : bm) + (long long)(kind >> 1) * 128;
#pragma unroll
        for (int r = 0; r < 2; ++r) {
            const int c   = tid + r * 512;     // chunk id 0..1023
            const int row = c >> 3;            // 0..127
            const int qg  = (c & 7) ^ (row & 7);
            GLDS16(src + (rbase + row) * K + (kt + qg * 8),
                   (char*)lds[slot] + c * 16);
        }
    };
    // read both k-halves of one A row-block i (2 x ds_read_b128)
    auto RD_A = [&](bf16x8 (&dst)[4][2], int slot, int i) {
        const int rl = wr * 64 + i * 16 + lrow;
        const bf16* base = &lds[slot][rl * 64];
#pragma unroll
        for (int h = 0; h < 2; ++h)
            dst[i][h] = *(const bf16x8*)(base + ((h * 4 + quad) ^ (rl & 7)) * 8);
    };
    auto RD_B = [&](bf16x8 (&dst)[2][2], int slot, int j) {
        const int rl = wc * 32 + j * 16 + lrow;
        const bf16* base = &lds[slot][rl * 64];
#pragma unroll
        for (int h = 0; h < 2; ++h)
            dst[j][h] = *(const bf16x8*)(base + ((h * 4 + quad) ^ (rl & 7)) * 8);
    };
    auto MFMAQ = [&](int mh, int nh, bf16x8 (&Af)[4][2], bf16x8 (&Bf)[2][2]) {
        __builtin_amdgcn_s_setprio(1);
#pragma unroll
        for (int h = 0; h < 2; ++h)
#pragma unroll
            for (int i = 0; i < 4; ++i)
#pragma unroll
                for (int j = 0; j < 2; ++j)
                    acc[mh][nh][i][j] = __builtin_amdgcn_mfma_f32_16x16x32_bf16(
                        Af[i][h], Bf[j][h], acc[mh][nh][i][j], 0, 0, 0);
        __builtin_amdgcn_s_setprio(0);
    };

    // one K-tile. MODE: 0 = steady, 1 = tile NT-2, 2 = tile NT-1 (last).
    auto BODY = [&](int T, auto modeTag,
                    bf16x8 (&a0c)[4][2], bf16x8 (&b0c)[2][2],
                    bf16x8 (&a0n)[4][2], bf16x8 (&b0n)[2][2]) {
        constexpr int MODE = decltype(modeTag)::value;
        const int bufb = (T & 1) * 4;
        const int nbuf = bufb ^ 4;
        const int P0   = 4 * T;
        bf16x8 a1[4][2], b1[2][2];       // tile-local frags

        // ---- q0: MFMA(0,0); read B1 + A1.i0; stage P0+6 ----
        RD_B(b1, bufb + 3, 0); RD_B(b1, bufb + 3, 1);
        RD_A(a1, bufb + 2, 0);
        if constexpr (MODE <= 1) STAGE(P0 + 6);   // exists: P0+6 <= 4NT-2
        MFMAQ(0, 0, a0c, b0c);
        SBAR();

        // ---- q1: MFMA(0,1); read A1.i1..3; stage P0+7 ----
        RD_A(a1, bufb + 2, 1); RD_A(a1, bufb + 2, 2); RD_A(a1, bufb + 2, 3);
        if constexpr (MODE <= 1) STAGE(P0 + 7);   // exists: P0+7 <= 4NT-1
        MFMAQ(0, 1, a0c, b1);
        if constexpr (MODE <= 1) VMCNT(6);        // stage P0+4 landed for q2
        SBAR();

        // ---- q2: MFMA(1,1); read next-tile A0.i0..2; stage P0+8 ----
        if constexpr (MODE != 2) {
            RD_A(a0n, nbuf + 0, 0); RD_A(a0n, nbuf + 0, 1); RD_A(a0n, nbuf + 0, 2);
        }
        if constexpr (MODE == 0) STAGE(P0 + 8);
        MFMAQ(1, 1, a1, b1);
        if constexpr (MODE == 0) { VMCNT(6); }    // stage P0+5 landed for q3
        else if constexpr (MODE == 1) { VMCNT(4); }
        SBAR();

        // ---- q3: MFMA(1,0); read next-tile A0.i3 + B0; stage P0+9 ----
        if constexpr (MODE != 2) {
            RD_A(a0n, nbuf + 0, 3);
            RD_B(b0n, nbuf + 1, 0); RD_B(b0n, nbuf + 1, 1);
        }
        if constexpr (MODE == 0) STAGE(P0 + 9);
        MFMAQ(1, 0, a1, b0c);
        if constexpr (MODE == 0) { VMCNT(4); }    // stages <= P0+7 landed
        else if constexpr (MODE == 1) { VMCNT(0); } // 4NT-2,4NT-1 landed
        SBAR();
    };

    // prologue: stages 0..5; own-wave vmcnt(4) -> stages 0..3 landed;
    // barrier makes it collective; THEN read tile 0's carried frags.
#pragma unroll
    for (int s = 0; s < 6; ++s) STAGE(s);
    VMCNT(4);
    SBAR();
#pragma unroll
    for (int i = 0; i < 4; ++i) RD_A(a0A, 0, i);
    RD_B(b0A, 1, 0); RD_B(b0A, 1, 1);

    for (int T = 0; T < NT - 2; T += 2) {
        BODY(T,     IC<0>{}, a0A, b0A, a0B, b0B);
        BODY(T + 1, IC<0>{}, a0B, b0B, a0A, b0A);
    }
    BODY(NT - 2, IC<1>{}, a0A, b0A, a0B, b0B);
    BODY(NT - 1, IC<2>{}, a0B, b0B, a0A, b0A);

    // epilogue: C/D layout col = lane&15, row = quad*4 + reg  [m89/m91]
#pragma unroll
    for (int nh = 0; nh < 2; ++nh)
#pragma unroll
        for (int j = 0; j < 2; ++j) {
            const long long gcol = bn + nh * 128 + wc * 32 + j * 16 + lrow;
            const float bv = bias[gcol];
#pragma unroll
            for (int mh = 0; mh < 2; ++mh)
#pragma unroll
                for (int i = 0; i < 4; ++i) {
                    const long long grow0 = bm + mh * 128 + wr * 64 + i * 16 + quad * 4;
#pragma unroll
                    for (int r = 0; r < 4; ++r)
                        C[(grow0 + r) * N + gcol] = (OutT)(acc[mh][nh][i][j][r] + bv);
                }
        }
}

// ---------------------------------------------------------------------------
// Causal depthwise conv1d (K=4, left pad 3) + bias + SiLU.  v2:
// 8 channels x 8 consecutive seq positions per thread; 11 X rows in regs,
// weights loaded once per 8 outputs. FMA order per output == v1.
// ---------------------------------------------------------------------------
__global__ __launch_bounds__(256)
void conv_silu_kernel(const bf16* __restrict__ X, const float* __restrict__ cw,
                      const float* __restrict__ cb, bf16* __restrict__ Y) {
    const int gid = blockIdx.x * 256 + threadIdx.x;
    const int c0  = (gid & 511) << 3;                 // channel base (8/thread)
    const long long bs0 = (long long)(gid >> 9) * 8;  // first output row
    const int s0  = (int)(bs0 & (SEQ - 1));

    float w[8][4];
#pragma unroll
    for (int j = 0; j < 8; ++j) {
        const float4 t = *(const float4*)(cw + (long long)(c0 + j) * 4);
        w[j][0] = t.x; w[j][1] = t.y; w[j][2] = t.z; w[j][3] = t.w;
    }
    float bv[8];
    {
        const float4 b0 = *(const float4*)(cb + c0);
        const float4 b1 = *(const float4*)(cb + c0 + 4);
        bv[0] = b0.x; bv[1] = b0.y; bv[2] = b0.z; bv[3] = b0.w;
        bv[4] = b1.x; bv[5] = b1.y; bv[6] = b1.z; bv[7] = b1.w;
    }

    B8 rows[11];
#pragma unroll
    for (int t = 0; t < 11; ++t) {
        if (s0 + t - 3 >= 0)
            rows[t].v = *(const uint4*)(X + (bs0 + t - 3) * CHANNELS + c0);
        else
            rows[t].v = uint4{0, 0, 0, 0};
    }

#pragma unroll
    for (int t = 0; t < 8; ++t) {
        B8 o;
#pragma unroll
        for (int j = 0; j < 8; ++j) {
            float a = bv[j];
            a += w[j][0] * (float)rows[t + 0].h[j];
            a += w[j][1] * (float)rows[t + 1].h[j];
            a += w[j][2] * (float)rows[t + 2].h[j];
            a += w[j][3] * (float)rows[t + 3].h[j];
            o.h[j] = (bf16)(a / (1.0f + __expf(-a)));
        }
        *(uint4*)(Y + (bs0 + t) * CHANNELS + c0) = o.v;
    }
}

// ---------------------------------------------------------------------------
extern "C" void kernel_launch(void* const* d_in, const int* in_sizes, int n_in,
                              void* d_out, int out_size, void* d_ws, size_t ws_size,
                              hipStream_t stream) {
    const float* hs    = (const float*)d_in[0];  // [4,4096,2048]
    const float* w_in  = (const float*)d_in[1];  // [4096,2048]
    const float* b_in  = (const float*)d_in[2];  // [4096]
    const float* cw    = (const float*)d_in[3];  // [4096,1,4]
    const float* cb    = (const float*)d_in[4];  // [4096]
    const float* w_out = (const float*)d_in[5];  // [2048,4096]
    const float* b_out = (const float*)d_in[6];  // [2048]
    float* out = (float*)d_out;                  // [4,4096,2048] fp32

    // ws layout (peak 272 MiB). Y overlaps hs_b/w_in_b — both dead before
    // conv writes Y (stream-ordered).
    char* ws = (char*)d_ws;
    bf16* X       = (bf16*)(ws);                           // [  0,128M)
    bf16* Y       = (bf16*)(ws + ((size_t)128 << 20));     // [128,256M)
    bf16* hs_b    = (bf16*)(ws + ((size_t)128 << 20));     // [128,192M) dies pre-conv
    bf16* w_in_b  = (bf16*)(ws + ((size_t)192 << 20));     // [192,208M) dies pre-conv
    bf16* w_out_b = (bf16*)(ws + ((size_t)256 << 20));     // [256,272M)

    cast_f32_to_bf16<<<(MTOT * HIDDEN) / (8 * 256), 256, 0, stream>>>(hs, hs_b);
    cast_f32_to_bf16<<<(CHANNELS * HIDDEN) / (8 * 256), 256, 0, stream>>>(w_in, w_in_b);
    cast_f32_to_bf16<<<(HIDDEN * CHANNELS) / (8 * 256), 256, 0, stream>>>(w_out, w_out_b);

    // GEMM1: X = hs @ w_in^T + b_in   [16384 x 4096], K=2048
    gemm256_bt_bias<bf16, CHANNELS, HIDDEN>
        <<<(MTOT / 256) * (CHANNELS / 256), 512, 0, stream>>>(hs_b, w_in_b, b_in, X);

    // conv + silu: Y = silu(causal_conv(X) + cb), 8 seq positions / thread
    conv_silu_kernel<<<(MTOT / 8) * (CHANNELS / 8) / 256, 256, 0, stream>>>(X, cw, cb, Y);

    // GEMM2: out = Y @ w_out^T + b_out   [16384 x 2048], K=4096  (fp32 out)
    gemm256_bt_bias<float, HIDDEN, CHANNELS>
        <<<(MTOT / 256) * (HIDDEN / 256), 512, 0, stream>>>(Y, w_out_b, b_out, out);
}